// Round 5
// baseline (140.151 us; speedup 1.0000x reference)
//
#include <hip/hip_runtime.h>
#include <hip/hip_bf16.h>

#define B_TOT 32768
#define OC 30
#define HID 100
#define TAGS 36

#define NI 32             // items per block
#define FS 212            // feats LDS stride in dwords (424 bf16: 416 K-pad + pad)
#define HS 68             // h LDS stride in dwords (136 bf16: 128 K-pad + pad)

// ws layout (dwords):
#define WS_T01 0          // f32[320000]  T0[c0]+T1[c1], oc padded to 32   (1.28 MB)
#define WS_T2R 320000     // f32[3200]    T2, 4-dword blocks rotated by c
#define WS_FC1 323200     // u32[23296]   fc1 bf16 B-frag packs
#define WS_OUT 346496     // u32[3072]    out bf16 B-frag packs
#define WS_TK  349568     // f32[9600]    raw Tk tables (prep scratch)

typedef __attribute__((ext_vector_type(8))) short short8;
typedef __attribute__((ext_vector_type(4))) float f32x4;

__device__ inline unsigned short f2bf(float f) {
    __hip_bfloat16 h = __float2bfloat16(f);
    return *reinterpret_cast<unsigned short*>(&h);
}
__device__ inline unsigned int pk_bf16(float a, float b) {
    return (unsigned int)f2bf(a) | ((unsigned int)f2bf(b) << 16);
}
__device__ inline short8 as8(uint4 u) {
    union { uint4 a; short8 b; } v; v.a = u; return v.b;
}

// ---- prep1: Tk[k][c][oc32] = sum_ce char_emb[c][ce] * conv_w[oc][ce][k] ----
__global__ void prep1(const float* __restrict__ conv_w,
                      const float* __restrict__ char_emb,
                      float* __restrict__ tk) {
    int idx = blockIdx.x * 256 + threadIdx.x;
    if (idx >= 9600) return;
    int oc = idx & 31, c = (idx >> 5) % 100, k = idx / 3200;
    float s = 0.f;
    if (oc < OC) {
        for (int ce = 0; ce < 32; ++ce)
            s += char_emb[c * 32 + ce] * conv_w[(oc * 32 + ce) * 3 + k];
    }
    tk[idx] = s;
}

// ---- prep2: T01 pair table + rotated T2 + MFMA B-frag packs ----
__global__ void prep2(const float* __restrict__ fc1_w,
                      const float* __restrict__ out_w,
                      unsigned int* __restrict__ ws) {
    int idx = blockIdx.x * 256 + threadIdx.x;
    const float* tk = (const float*)ws + WS_TK;
    float* wsf = (float*)ws;
    if (idx < 320000) {
        int oc = idx & 31, pair = idx >> 5;
        int c1 = pair % 100, c0 = pair / 100;
        wsf[WS_T01 + idx] = tk[c0 * 32 + oc] + tk[3200 + c1 * 32 + oc];
    } else if (idx < 323200) {
        // phys dword (blk,d) of row c holds logical oc = ((blk-c)&7)*4+d
        int t = idx - 320000;
        int dw = t & 31, c = t >> 5;
        int blk = dw >> 2, d = dw & 3;
        int oc = (((blk - c) & 7) << 2) + d;
        wsf[WS_T2R + t] = tk[6400 + c * 32 + oc];
    } else if (idx < 323200 + 23296) {
        // fc1 B-frag chunks: [(nt*13+ks)][lane][dw] ; n=lane&15, k=ks*32+(lane>>4)*8+dw*2
        int t = idx - 323200;
        int dw = t & 3, lane = (t >> 2) & 63, chunk = t >> 8;
        int ks = chunk % 13, nt = chunk / 13;
        int j = nt * 16 + (lane & 15);
        int k = ks * 32 + (lane >> 4) * 8 + dw * 2;
        float a = (j < HID && k     < 400) ? fc1_w[j * 400 + k]     : 0.f;
        float b = (j < HID && k + 1 < 400) ? fc1_w[j * 400 + k + 1] : 0.f;
        ws[WS_FC1 + t] = pk_bf16(a, b);
    } else if (idx < 346496 + 3072) {
        int t = idx - 346496;
        int dw = t & 3, lane = (t >> 2) & 63, chunk = t >> 8;
        int ks = chunk % 4, nt = chunk / 4;
        int j = nt * 16 + (lane & 15);
        int k = ks * 32 + (lane >> 4) * 8 + dw * 2;
        float a = (j < TAGS && k     < HID) ? out_w[j * 100 + k]     : 0.f;
        float b = (j < TAGS && k + 1 < HID) ? out_w[j * 100 + k + 1] : 0.f;
        ws[WS_OUT + t] = pk_bf16(a, b);
    }
}

// ---------------- fused main ----------------
__global__ __launch_bounds__(256, 3)
void pos_fused(const int*   __restrict__ input,   // (B, 105)
               const float* __restrict__ emb,     // (WV, 50)
               const float* __restrict__ conv_b,  // (30)
               const float* __restrict__ fc1_b,   // (100)
               const float* __restrict__ out_b,   // (36)
               const unsigned int* __restrict__ ws,
               float*       __restrict__ out)     // (B, 36)
{
    __shared__ unsigned int F[NI * FS];   // feats bf16x2, A-layout, 27136 B
    __shared__ float        T2s[3200];    // rotated T2 table, 12800 B
    __shared__ unsigned int Hh[NI * HS];  // h bf16x2, 8704 B

    const int tid   = threadIdx.x;
    const int item0 = blockIdx.x * NI;
    const float* wsf = (const float*)ws;

    // ---- stage rotated T2; zero K-pads ----
    for (int idx = tid; idx < 3200; idx += 256) T2s[idx] = wsf[WS_T2R + idx];
    for (int idx = tid; idx < NI * 12; idx += 256) F[(idx / 12) * FS + 200 + idx % 12] = 0;
    for (int idx = tid; idx < NI * 18; idx += 256) Hh[(idx / 18) * HS + 50 + idx % 18] = 0;

    // ---- word embeddings -> F (bf16 pairs) ----
    for (int idx = tid; idx < NI * 5 * 25; idx += 256) {
        int ph = idx % 25;
        int w  = (idx / 25) % 5;
        int i  = idx / 125;
        int wid = input[(item0 + i) * 105 + w * 21];
        float2 e = *(const float2*)&emb[wid * 50 + ph * 2];
        F[i * FS + w * 40 + ph] = pk_bf16(e.x, e.y);
    }
    __syncthreads();   // T2s ready

    // ---- conv + maxpool: 8 lanes per (i,w), lane = 4 oc ----
    {
        const int q8  = tid & 7;
        const int grp = tid >> 3;                 // 0..31
        const int oc0 = q8 * 4;
        const float4* t01 = (const float4*)(wsf + WS_T01);
        const float b0 = conv_b[oc0];
        const float b1 = conv_b[oc0 + 1];
        const float b2 = (oc0 + 2 < OC) ? conv_b[oc0 + 2] : 0.f;
        const float b3 = (oc0 + 3 < OC) ? conv_b[oc0 + 3] : 0.f;
        for (int round = 0; round < 5; ++round) {
            int task = round * 32 + grp;          // 0..159
            int i = task / 5, w = task % 5;
            const int* cp = &input[(item0 + i) * 105 + w * 21 + 1];
            int c[20];
            #pragma unroll
            for (int p = 0; p < 20; ++p) c[p] = cp[p];
            float m0 = -1e30f, m1 = -1e30f, m2 = -1e30f, m3 = -1e30f;
            #pragma unroll 6
            for (int p = 0; p < 18; ++p) {
                float4 a = t01[(c[p] * 100 + c[p + 1]) * 8 + q8];
                int c2 = c[p + 2];
                float4 b = *(const float4*)&T2s[c2 * 32 + (((q8 + c2) & 7) << 2)];
                m0 = fmaxf(m0, a.x + b.x);
                m1 = fmaxf(m1, a.y + b.y);
                m2 = fmaxf(m2, a.z + b.z);
                m3 = fmaxf(m3, a.w + b.w);
            }
            F[i * FS + w * 40 + 25 + q8 * 2] = pk_bf16(m0 + b0, m1 + b1);
            if (oc0 + 2 < OC)
                F[i * FS + w * 40 + 25 + q8 * 2 + 1] = pk_bf16(m2 + b2, m3 + b3);
        }
    }
    __syncthreads();   // F ready

    // ---- fc1: MFMA 16x16x32 bf16. wave -> (msub, n-half) ----
    const int wv   = tid >> 6;
    const int lane = tid & 63;
    const int ln15 = lane & 15;
    const int quad = lane >> 4;
    {
        const int msub = wv & 1;
        const int nh   = wv >> 1;
        const int nt0  = nh * 4;
        const int NT   = nh ? 3 : 4;               // n-tiles 0..3 / 4..6 (N=112)
        const int m0   = msub * 16;
        f32x4 acc[4] = {f32x4{0,0,0,0}, f32x4{0,0,0,0}, f32x4{0,0,0,0}, f32x4{0,0,0,0}};
        const uint4* wp = (const uint4*)(ws + WS_FC1);
        const int aoff = (m0 + ln15) * FS + quad * 4;
        for (int ks = 0; ks < 13; ++ks) {
            short8 a = as8(*(const uint4*)&F[aoff + ks * 16]);
            #pragma unroll
            for (int t = 0; t < 4; ++t) {
                if (t < NT) {
                    uint4 bv = wp[((nt0 + t) * 13 + ks) * 64 + lane];
                    acc[t] = __builtin_amdgcn_mfma_f32_16x16x32_bf16(a, as8(bv), acc[t], 0, 0, 0);
                }
            }
        }
        #pragma unroll
        for (int t = 0; t < 4; ++t) {
            if (t < NT) {
                int j = (nt0 + t) * 16 + ln15;     // C col = lane&15
                if (j < HID) {
                    float bj = fc1_b[j];
                    #pragma unroll
                    for (int r = 0; r < 4; ++r) {
                        int it = m0 + quad * 4 + r; // C row = quad*4+reg
                        float hv = tanhf(acc[t][r] + bj);
                        ((unsigned short*)Hh)[it * (HS * 2) + j] = f2bf(hv);
                    }
                }
            }
        }
    }
    __syncthreads();   // Hh ready

    // ---- out layer: MFMA, N=48 (3 tiles), K=128 (4 steps) ----
    {
        const int msub = wv & 1;
        const int nh   = wv >> 1;
        const int nt0  = nh * 2;
        const int NT   = nh ? 1 : 2;               // n-tiles 0,1 / 2
        const int m0   = msub * 16;
        f32x4 acc[2] = {f32x4{0,0,0,0}, f32x4{0,0,0,0}};
        const uint4* wp = (const uint4*)(ws + WS_OUT);
        const int aoff = (m0 + ln15) * HS + quad * 4;
        #pragma unroll
        for (int ks = 0; ks < 4; ++ks) {
            short8 a = as8(*(const uint4*)&Hh[aoff + ks * 16]);
            #pragma unroll
            for (int t = 0; t < 2; ++t) {
                if (t < NT) {
                    uint4 bv = wp[((nt0 + t) * 4 + ks) * 64 + lane];
                    acc[t] = __builtin_amdgcn_mfma_f32_16x16x32_bf16(a, as8(bv), acc[t], 0, 0, 0);
                }
            }
        }
        #pragma unroll
        for (int t = 0; t < 2; ++t) {
            if (t < NT) {
                int o = (nt0 + t) * 16 + ln15;
                if (o < TAGS) {
                    float bo = out_b[o];
                    #pragma unroll
                    for (int r = 0; r < 4; ++r) {
                        int it = item0 + m0 + quad * 4 + r;
                        out[it * TAGS + o] = acc[t][r] + bo;
                    }
                }
            }
        }
    }
}

extern "C" void kernel_launch(void* const* d_in, const int* in_sizes, int n_in,
                              void* d_out, int out_size, void* d_ws, size_t ws_size,
                              hipStream_t stream) {
    const int*   input  = (const int*)  d_in[0];
    const float* emb    = (const float*)d_in[1];
    const float* char_e = (const float*)d_in[2];
    const float* conv_w = (const float*)d_in[3];
    const float* conv_b = (const float*)d_in[4];
    const float* fc1_w  = (const float*)d_in[5];
    const float* fc1_b  = (const float*)d_in[6];
    const float* out_w  = (const float*)d_in[7];
    const float* out_b  = (const float*)d_in[8];
    unsigned int* ws = (unsigned int*)d_ws;

    prep1<<<38, 256, 0, stream>>>(conv_w, char_e, (float*)ws + WS_TK);
    prep2<<<1366, 256, 0, stream>>>(fc1_w, out_w, ws);
    pos_fused<<<B_TOT / NI, 256, 0, stream>>>(input, emb, conv_b, fc1_b, out_b,
                                              ws, (float*)d_out);
}

// Round 7
// 135.605 us; speedup vs baseline: 1.0335x; 1.0335x over previous
//
#include <hip/hip_runtime.h>

#define B_TOT 32768
#define OC 30
#define HID 100
#define TAGS 36

#define NI 16             // items per block
#define FS 212            // feats LDS stride in dwords (424 fp16: 416 K-pad + pad)
#define HS 68             // h LDS stride in dwords (136 fp16: 128 K-pad + pad)

// ws layout (dwords): TH fp16x2[6000] @0 ; fc1 packs @6000 ; out packs @29296
#define WS_TH  0
#define WS_FC1 6000
#define WS_OUT 29296

typedef __attribute__((ext_vector_type(8))) _Float16 half8;
typedef __attribute__((ext_vector_type(2))) _Float16 h2v;
typedef __attribute__((ext_vector_type(4))) float f32x4;

__device__ inline half8 ash8(uint4 u) {
    union { uint4 a; half8 b; } v; v.a = u; return v.b;
}
__device__ inline unsigned int h2u(h2v h) {
    union { h2v a; unsigned int b; } v; v.a = h; return v.b;
}
__device__ inline h2v u2h(unsigned int u) {
    union { unsigned int a; h2v b; } v; v.a = u; return v.b;
}
__device__ inline unsigned int pk_f16(float a, float b) {
    h2v h; h.x = (_Float16)a; h.y = (_Float16)b; return h2u(h);
}

// ---------------- prep: fp16 T tables + fp16 MFMA B-frag packs ----------------
__global__ void prep(const float* __restrict__ conv_w,   // (30,32,3)
                     const float* __restrict__ char_emb, // (100,32)
                     const float* __restrict__ fc1_w,    // (100,400)
                     const float* __restrict__ out_w,    // (36,100)
                     unsigned int* __restrict__ ws) {
    int idx = blockIdx.x * 256 + threadIdx.x;
    if (idx < 6000) {
        // TH[k][c][20 dwords]: row = 40 fp16 (32 used) -> 80 B rows, 8 bank phases
        int rd = idx % 20, row = idx / 20;
        int c = row % 100, k = row / 100;
        float v[2];
        #pragma unroll
        for (int e = 0; e < 2; ++e) {
            int oc = rd * 2 + e;
            float s = 0.f;
            if (oc < OC) {
                for (int ce = 0; ce < 32; ++ce)
                    s += char_emb[c * 32 + ce] * conv_w[(oc * 32 + ce) * 3 + k];
            }
            v[e] = s;
        }
        ws[WS_TH + idx] = pk_f16(v[0], v[1]);
    } else if (idx < 6000 + 23296) {
        // fc1 B-frag chunks: [(nt*13+ks)][lane][dw] ; n=lane&15, k=ks*32+(lane>>4)*8+dw*2
        int t = idx - 6000;
        int dw = t & 3, lane = (t >> 2) & 63, chunk = t >> 8;
        int ks = chunk % 13, nt = chunk / 13;
        int j = nt * 16 + (lane & 15);
        int k = ks * 32 + (lane >> 4) * 8 + dw * 2;
        float a = (j < HID && k     < 400) ? fc1_w[j * 400 + k]     : 0.f;
        float b = (j < HID && k + 1 < 400) ? fc1_w[j * 400 + k + 1] : 0.f;
        ws[WS_FC1 + t] = pk_f16(a, b);
    } else if (idx < 29296 + 3072) {
        int t = idx - 29296;
        int dw = t & 3, lane = (t >> 2) & 63, chunk = t >> 8;
        int ks = chunk % 4, nt = chunk / 4;
        int j = nt * 16 + (lane & 15);
        int k = ks * 32 + (lane >> 4) * 8 + dw * 2;
        float a = (j < TAGS && k     < HID) ? out_w[j * 100 + k]     : 0.f;
        float b = (j < TAGS && k + 1 < HID) ? out_w[j * 100 + k + 1] : 0.f;
        ws[WS_OUT + t] = pk_f16(a, b);
    }
}

// ---------------- fused main ----------------
__global__ __launch_bounds__(256)
void pos_fused(const int*   __restrict__ input,   // (B, 105)
               const float* __restrict__ emb,     // (WV, 50)
               const float* __restrict__ conv_b,  // (30)
               const float* __restrict__ fc1_b,   // (100)
               const float* __restrict__ out_b,   // (36)
               const unsigned int* __restrict__ ws,
               float*       __restrict__ out)     // (B, 36)
{
    __shared__ unsigned int Ths[6000];    // fp16 T tables, 24000 B
    __shared__ unsigned int F[NI * FS];   // feats fp16x2, A-layout, 13568 B
    __shared__ int          ids[NI * 105];// 6720 B
    __shared__ unsigned int Hh[NI * HS];  // h fp16x2, 4352 B

    const int tid   = threadIdx.x;
    const int item0 = blockIdx.x * NI;

    // ---- phase 0: stage T + ids, zero K-pads ----
    for (int idx = tid; idx < 6000; idx += 256) Ths[idx] = ws[WS_TH + idx];
    const int* inp = input + item0 * 105;
    for (int idx = tid; idx < NI * 105; idx += 256) ids[idx] = inp[idx];
    for (int idx = tid; idx < NI * 12; idx += 256) F[(idx / 12) * FS + 200 + idx % 12] = 0;
    for (int idx = tid; idx < NI * 18; idx += 256) Hh[(idx / 18) * HS + 50 + idx % 18] = 0;
    __syncthreads();

    // ---- phase 1a: word embeddings -> F (fp16 pairs) ----
    for (int idx = tid; idx < NI * 5 * 25; idx += 256) {
        int ph = idx % 25;
        int w  = (idx / 25) % 5;
        int i  = idx / 125;
        int wid = ids[i * 105 + w * 21];
        float2 e = *(const float2*)&emb[wid * 50 + ph * 2];
        F[i * FS + w * 40 + ph] = pk_f16(e.x, e.y);
    }

    // ---- phase 1b: conv + maxpool, 4 lanes per (i,w), lane = 8 oc (packed fp16) ----
    {
        const int q4  = tid & 3;
        const int grp = tid >> 2;                 // 0..63
        const int oc0 = q4 * 8;
        h2v bias[4];
        #pragma unroll
        for (int d = 0; d < 4; ++d) {
            int a = oc0 + 2 * d, b = a + 1;
            bias[d].x = (_Float16)(a < OC ? conv_b[a] : 0.f);
            bias[d].y = (_Float16)(b < OC ? conv_b[b] : 0.f);
        }
        for (int task = grp; task < NI * 5; task += 64) {
            int i = task / 5, w = task % 5;
            const int* cp = &ids[i * 105 + w * 21 + 1];
            int c[20];
            #pragma unroll
            for (int p = 0; p < 20; ++p) c[p] = cp[p];
            h2v m[4];
            #pragma unroll
            for (int d = 0; d < 4; ++d) { m[d].x = (_Float16)(-30000.f); m[d].y = (_Float16)(-30000.f); }
            #pragma unroll 6
            for (int p = 0; p < 18; ++p) {
                uint4 ra = *(const uint4*)&Ths[c[p    ] * 20        + q4 * 4];
                uint4 rb = *(const uint4*)&Ths[c[p + 1] * 20 + 2000 + q4 * 4];
                uint4 rc = *(const uint4*)&Ths[c[p + 2] * 20 + 4000 + q4 * 4];
                unsigned int* pa = (unsigned int*)&ra;
                unsigned int* pb = (unsigned int*)&rb;
                unsigned int* pc = (unsigned int*)&rc;
                #pragma unroll
                for (int d = 0; d < 4; ++d) {
                    h2v s = u2h(pa[d]) + u2h(pb[d]) + u2h(pc[d]);
                    m[d] = __builtin_elementwise_max(m[d], s);
                }
            }
            int base = i * FS + w * 40 + 25 + q4 * 4;
            F[base]     = h2u(m[0] + bias[0]);
            F[base + 1] = h2u(m[1] + bias[1]);
            F[base + 2] = h2u(m[2] + bias[2]);
            if (q4 < 3) F[base + 3] = h2u(m[3] + bias[3]);
        }
    }
    __syncthreads();   // F ready

    // ---- phase 2: fc1 MFMA 16x16x32 f16, M=16, wave -> 2 n-tiles ----
    const int wv   = tid >> 6;
    const int lane = tid & 63;
    const int ln15 = lane & 15;
    const int quad = lane >> 4;
    {
        const int nt0 = wv * 2;
        const int NT  = (wv < 3) ? 2 : 1;          // 7 n-tiles (N=112)
        f32x4 acc[2] = {f32x4{0,0,0,0}, f32x4{0,0,0,0}};
        const uint4* wp = (const uint4*)(ws + WS_FC1);
        const int aoff = ln15 * FS + quad * 4;
        for (int ks = 0; ks < 13; ++ks) {
            half8 a = ash8(*(const uint4*)&F[aoff + ks * 16]);
            #pragma unroll
            for (int t = 0; t < 2; ++t) {
                if (t < NT) {
                    uint4 bv = wp[((nt0 + t) * 13 + ks) * 64 + lane];
                    acc[t] = __builtin_amdgcn_mfma_f32_16x16x32_f16(a, ash8(bv), acc[t], 0, 0, 0);
                }
            }
        }
        #pragma unroll
        for (int t = 0; t < 2; ++t) {
            if (t < NT) {
                int j = (nt0 + t) * 16 + ln15;     // C col = lane&15
                if (j < HID) {
                    float bj = fc1_b[j];
                    #pragma unroll
                    for (int r = 0; r < 4; ++r) {
                        int it = quad * 4 + r;     // C row = quad*4+reg
                        float hv = tanhf(acc[t][r] + bj);
                        _Float16 h = (_Float16)hv;
                        ((unsigned short*)Hh)[it * (HS * 2) + j] =
                            *reinterpret_cast<unsigned short*>(&h);
                    }
                }
            }
        }
    }
    __syncthreads();   // Hh ready

    // ---- phase 3: out layer MFMA, N=48 (3 tiles over waves 0-2), K=128 ----
    if (wv < 3) {
        f32x4 acc = f32x4{0, 0, 0, 0};
        const uint4* wp = (const uint4*)(ws + WS_OUT);
        const int aoff = ln15 * HS + quad * 4;
        #pragma unroll
        for (int ks = 0; ks < 4; ++ks) {
            half8 a = ash8(*(const uint4*)&Hh[aoff + ks * 16]);
            uint4 bv = wp[(wv * 4 + ks) * 64 + lane];
            acc = __builtin_amdgcn_mfma_f32_16x16x32_f16(a, ash8(bv), acc, 0, 0, 0);
        }
        int o = wv * 16 + ln15;
        if (o < TAGS) {
            float bo = out_b[o];
            #pragma unroll
            for (int r = 0; r < 4; ++r) {
                int it = item0 + quad * 4 + r;
                out[it * TAGS + o] = acc[r] + bo;
            }
        }
    }
}

extern "C" void kernel_launch(void* const* d_in, const int* in_sizes, int n_in,
                              void* d_out, int out_size, void* d_ws, size_t ws_size,
                              hipStream_t stream) {
    const int*   input  = (const int*)  d_in[0];
    const float* emb    = (const float*)d_in[1];
    const float* char_e = (const float*)d_in[2];
    const float* conv_w = (const float*)d_in[3];
    const float* conv_b = (const float*)d_in[4];
    const float* fc1_w  = (const float*)d_in[5];
    const float* fc1_b  = (const float*)d_in[6];
    const float* out_w  = (const float*)d_in[7];
    const float* out_b  = (const float*)d_in[8];
    unsigned int* ws = (unsigned int*)d_ws;

    prep<<<127, 256, 0, stream>>>(conv_w, char_e, fc1_w, out_w, ws);
    pos_fused<<<B_TOT / NI, 256, 0, stream>>>(input, emb, conv_b, fc1_b, out_b,
                                              ws, (float*)d_out);
}

// Round 8
// 127.930 us; speedup vs baseline: 1.0955x; 1.0600x over previous
//
#include <hip/hip_runtime.h>

#define B_TOT 32768
#define OC 30
#define HID 100
#define TAGS 36

// ws layout (dwords): TH fp16x2[6000] @0 ; fc1 packs @6000 ; out packs @29296
#define WS_TH  0
#define WS_FC1 6000
#define WS_OUT 29296

typedef __attribute__((ext_vector_type(8))) _Float16 half8;
typedef __attribute__((ext_vector_type(2))) _Float16 h2v;
typedef __attribute__((ext_vector_type(4))) float f32x4;

__device__ inline half8 ash8(uint4 u) {
    union { uint4 a; half8 b; } v; v.a = u; return v.b;
}
__device__ inline unsigned int h2u(h2v h) {
    union { h2v a; unsigned int b; } v; v.a = h; return v.b;
}
__device__ inline h2v u2h(unsigned int u) {
    union { unsigned int a; h2v b; } v; v.a = u; return v.b;
}
__device__ inline unsigned int pk_f16(float a, float b) {
    h2v h; h.x = (_Float16)a; h.y = (_Float16)b; return h2u(h);
}

// ---------------- prep: fp16 T tables + fp16 MFMA B-frag packs (same as r7) ----------------
__global__ void prep(const float* __restrict__ conv_w,   // (30,32,3)
                     const float* __restrict__ char_emb, // (100,32)
                     const float* __restrict__ fc1_w,    // (100,400)
                     const float* __restrict__ out_w,    // (36,100)
                     unsigned int* __restrict__ ws) {
    int idx = blockIdx.x * 256 + threadIdx.x;
    if (idx < 6000) {
        // TH[k][c][20 dwords]: row = 40 fp16 (32 used) -> 80 B rows, 8 bank phases
        int rd = idx % 20, row = idx / 20;
        int c = row % 100, k = row / 100;
        float v[2];
        #pragma unroll
        for (int e = 0; e < 2; ++e) {
            int oc = rd * 2 + e;
            float s = 0.f;
            if (oc < OC) {
                for (int ce = 0; ce < 32; ++ce)
                    s += char_emb[c * 32 + ce] * conv_w[(oc * 32 + ce) * 3 + k];
            }
            v[e] = s;
        }
        ws[WS_TH + idx] = pk_f16(v[0], v[1]);
    } else if (idx < 6000 + 23296) {
        // fc1 B-frag chunks: [(nt*13+ks)][lane][dw] ; n=lane&15, k=ks*32+(lane>>4)*8+dw*2
        int t = idx - 6000;
        int dw = t & 3, lane = (t >> 2) & 63, chunk = t >> 8;
        int ks = chunk % 13, nt = chunk / 13;
        int j = nt * 16 + (lane & 15);
        int k = ks * 32 + (lane >> 4) * 8 + dw * 2;
        float a = (j < HID && k     < 400) ? fc1_w[j * 400 + k]     : 0.f;
        float b = (j < HID && k + 1 < 400) ? fc1_w[j * 400 + k + 1] : 0.f;
        ws[WS_FC1 + t] = pk_f16(a, b);
    } else if (idx < 29296 + 3072) {
        int t = idx - 29296;
        int dw = t & 3, lane = (t >> 2) & 63, chunk = t >> 8;
        int ks = chunk % 4, nt = chunk / 4;
        int j = nt * 16 + (lane & 15);
        int k = ks * 32 + (lane >> 4) * 8 + dw * 2;
        float a = (j < TAGS && k     < HID) ? out_w[j * 100 + k]     : 0.f;
        float b = (j < TAGS && k + 1 < HID) ? out_w[j * 100 + k + 1] : 0.f;
        ws[WS_OUT + t] = pk_f16(a, b);
    }
}

// ---------------- fused main: one wave = 16 items end-to-end, 1 barrier total ----------------
__global__ __launch_bounds__(256, 2)
void pos_fused(const int*   __restrict__ input,   // (B, 105)
               const float* __restrict__ emb,     // (WV, 50)
               const float* __restrict__ conv_b,  // (30)
               const float* __restrict__ fc1_b,   // (100)
               const float* __restrict__ out_b,   // (36)
               const unsigned int* __restrict__ ws,
               float*       __restrict__ out)     // (B, 36)
{
    __shared__ unsigned int Ths[6000];        // fp16 T tables, 24000 B (block-shared, RO)
    __shared__ unsigned int F[4][16 * 212];   // per-wave feats slice, 13568 B each

    const int tid  = threadIdx.x;
    const int wv   = tid >> 6;
    const int lane = tid & 63;
    const int ln15 = lane & 15;
    const int quad = lane >> 4;
    const int item0 = blockIdx.x * 64 + wv * 16;
    unsigned int* Fw = &F[wv][0];

    // ---- stage T tables (whole block), the only barrier ----
    for (int idx = tid; idx < 6000; idx += 256) Ths[idx] = ws[WS_TH + idx];
    __syncthreads();

    // ---- per-wave: zero F K-pad (dwords 200..207 per item row) ----
    {
        int i = lane >> 2, d0 = 200 + (lane & 3) * 2;
        Fw[i * 212 + d0]     = 0;
        Fw[i * 212 + d0 + 1] = 0;
    }

    // ---- word embeddings -> Fw (fp16 pairs), 2000 dwords per wave ----
    for (int t = 0; t < 32; ++t) {
        int idx = t * 64 + lane;
        if (idx < 2000) {
            int ph = idx % 25;
            int w  = (idx / 25) % 5;
            int i  = idx / 125;
            int wid = input[(item0 + i) * 105 + w * 21];
            float2 e = *(const float2*)&emb[wid * 50 + ph * 2];
            Fw[i * 212 + w * 40 + ph] = pk_f16(e.x, e.y);
        }
    }

    // ---- conv + maxpool: 4 lanes per (i,w), lane = 8 oc (packed fp16) ----
    {
        const int q4  = lane & 3;
        const int grp = lane >> 2;                // 0..15
        const int oc0 = q4 * 8;
        h2v bias[4];
        #pragma unroll
        for (int d = 0; d < 4; ++d) {
            int a = oc0 + 2 * d, b = a + 1;
            bias[d].x = (_Float16)(a < OC ? conv_b[a] : 0.f);
            bias[d].y = (_Float16)(b < OC ? conv_b[b] : 0.f);
        }
        #pragma unroll
        for (int round = 0; round < 5; ++round) {
            int task = round * 16 + grp;          // 0..79
            int i = task / 5, w = task % 5;
            const int* cp = &input[(item0 + i) * 105 + w * 21 + 1];
            int c[20];
            #pragma unroll
            for (int p = 0; p < 20; ++p) c[p] = cp[p];
            h2v m[4];
            #pragma unroll
            for (int d = 0; d < 4; ++d) { m[d].x = (_Float16)(-30000.f); m[d].y = (_Float16)(-30000.f); }
            #pragma unroll 6
            for (int p = 0; p < 18; ++p) {
                uint4 ra = *(const uint4*)&Ths[c[p    ] * 20        + q4 * 4];
                uint4 rb = *(const uint4*)&Ths[c[p + 1] * 20 + 2000 + q4 * 4];
                uint4 rc = *(const uint4*)&Ths[c[p + 2] * 20 + 4000 + q4 * 4];
                unsigned int* pa = (unsigned int*)&ra;
                unsigned int* pb = (unsigned int*)&rb;
                unsigned int* pc = (unsigned int*)&rc;
                #pragma unroll
                for (int d = 0; d < 4; ++d) {
                    h2v s = u2h(pa[d]) + u2h(pb[d]) + u2h(pc[d]);
                    m[d] = __builtin_elementwise_max(m[d], s);
                }
            }
            int base = i * 212 + w * 40 + 25 + q4 * 4;
            Fw[base]     = h2u(m[0] + bias[0]);
            Fw[base + 1] = h2u(m[1] + bias[1]);
            Fw[base + 2] = h2u(m[2] + bias[2]);
            if (q4 < 3) Fw[base + 3] = h2u(m[3] + bias[3]);
        }
    }
    // no barrier: same-wave LDS writes are visible to same-wave later reads (in-order DS pipe)

    // ---- fc1: MFMA 16x16x32 f16, M = wave's 16 items, all 7 n-tiles ----
    f32x4 acc[7];
    #pragma unroll
    for (int t = 0; t < 7; ++t) acc[t] = f32x4{0, 0, 0, 0};
    {
        const uint4* wp = (const uint4*)(ws + WS_FC1);
        const int aoff = ln15 * 212 + quad * 4;
        for (int ks = 0; ks < 13; ++ks) {
            half8 a = ash8(*(const uint4*)&Fw[aoff + ks * 16]);
            #pragma unroll
            for (int t = 0; t < 7; ++t) {
                uint4 bv = wp[(t * 13 + ks) * 64 + lane];
                acc[t] = __builtin_amdgcn_mfma_f32_16x16x32_f16(a, ash8(bv), acc[t], 0, 0, 0);
            }
        }
    }

    // ---- epilogue: overlay Hh (stride 68 dwords) onto Fw; zero K-pad; tanh ----
    {
        // zero Hh pad dwords 50..63 per item (k=100..127)
        for (int t2 = lane; t2 < 224; t2 += 64) {
            int i = t2 / 14, d = t2 % 14;
            Fw[i * 68 + 50 + d] = 0;
        }
        unsigned short* Hw = (unsigned short*)Fw;
        #pragma unroll
        for (int t = 0; t < 7; ++t) {
            int j = t * 16 + ln15;
            if (j < HID) {
                float bj = fc1_b[j];
                #pragma unroll
                for (int r = 0; r < 4; ++r) {
                    int it = quad * 4 + r;
                    float hv = tanhf(acc[t][r] + bj);
                    _Float16 h = (_Float16)hv;
                    Hw[it * 136 + j] = *reinterpret_cast<unsigned short*>(&h);
                }
            }
        }
    }

    // ---- out layer: MFMA, 3 n-tiles, K=128 ----
    {
        f32x4 oacc[3];
        #pragma unroll
        for (int t = 0; t < 3; ++t) oacc[t] = f32x4{0, 0, 0, 0};
        const uint4* wpo = (const uint4*)(ws + WS_OUT);
        const int aoff2 = ln15 * 68 + quad * 4;
        #pragma unroll
        for (int ks = 0; ks < 4; ++ks) {
            half8 a = ash8(*(const uint4*)&Fw[aoff2 + ks * 16]);
            #pragma unroll
            for (int t = 0; t < 3; ++t) {
                uint4 bv = wpo[(t * 4 + ks) * 64 + lane];
                oacc[t] = __builtin_amdgcn_mfma_f32_16x16x32_f16(a, ash8(bv), oacc[t], 0, 0, 0);
            }
        }
        #pragma unroll
        for (int t = 0; t < 3; ++t) {
            int o = t * 16 + ln15;
            if (o < TAGS) {
                float bo = out_b[o];
                #pragma unroll
                for (int r = 0; r < 4; ++r) {
                    int it = item0 + quad * 4 + r;
                    out[it * TAGS + o] = oacc[t][r] + bo;
                }
            }
        }
    }
}

extern "C" void kernel_launch(void* const* d_in, const int* in_sizes, int n_in,
                              void* d_out, int out_size, void* d_ws, size_t ws_size,
                              hipStream_t stream) {
    const int*   input  = (const int*)  d_in[0];
    const float* emb    = (const float*)d_in[1];
    const float* char_e = (const float*)d_in[2];
    const float* conv_w = (const float*)d_in[3];
    const float* conv_b = (const float*)d_in[4];
    const float* fc1_w  = (const float*)d_in[5];
    const float* fc1_b  = (const float*)d_in[6];
    const float* out_w  = (const float*)d_in[7];
    const float* out_b  = (const float*)d_in[8];
    unsigned int* ws = (unsigned int*)d_ws;

    prep<<<127, 256, 0, stream>>>(conv_w, char_e, fc1_w, out_w, ws);
    pos_fused<<<B_TOT / 64, 256, 0, stream>>>(input, emb, conv_b, fc1_b, out_b,
                                              ws, (float*)d_out);
}

// Round 9
// 127.390 us; speedup vs baseline: 1.1002x; 1.0042x over previous
//
#include <hip/hip_runtime.h>

#define B_TOT 32768
#define OC 30
#define HID 100
#define TAGS 36

// ws layout (dwords):
#define WS_TH  0          // fp16x2[6000]  T tables
#define WS_FC1 6000       // u32[23296]    fc1 B-frag packs
#define WS_OUT 29296      // u32[3072]     out B-frag packs
#define WS_F   40960      // u32[32768*208] fp16 feature rows (27.3 MB)

typedef __attribute__((ext_vector_type(8))) _Float16 half8;
typedef __attribute__((ext_vector_type(2))) _Float16 h2v;
typedef __attribute__((ext_vector_type(4))) float f32x4;

__device__ inline half8 ash8(uint4 u) {
    union { uint4 a; half8 b; } v; v.a = u; return v.b;
}
__device__ inline unsigned int h2u(h2v h) {
    union { h2v a; unsigned int b; } v; v.a = h; return v.b;
}
__device__ inline h2v u2h(unsigned int u) {
    union { unsigned int a; h2v b; } v; v.a = u; return v.b;
}
__device__ inline unsigned int pk_f16(float a, float b) {
    h2v h; h.x = (_Float16)a; h.y = (_Float16)b; return h2u(h);
}

// ---------------- prep: fp16 T tables + fp16 MFMA B-frag packs ----------------
__global__ void prep(const float* __restrict__ conv_w,   // (30,32,3)
                     const float* __restrict__ char_emb, // (100,32)
                     const float* __restrict__ fc1_w,    // (100,400)
                     const float* __restrict__ out_w,    // (36,100)
                     unsigned int* __restrict__ ws) {
    int idx = blockIdx.x * 256 + threadIdx.x;
    if (idx < 6000) {
        // TH[k][c][20 dwords]: row = 40 fp16 (32 used) -> 80 B rows
        int rd = idx % 20, row = idx / 20;
        int c = row % 100, k = row / 100;
        float v[2];
        #pragma unroll
        for (int e = 0; e < 2; ++e) {
            int oc = rd * 2 + e;
            float s = 0.f;
            if (oc < OC) {
                for (int ce = 0; ce < 32; ++ce)
                    s += char_emb[c * 32 + ce] * conv_w[(oc * 32 + ce) * 3 + k];
            }
            v[e] = s;
        }
        ws[WS_TH + idx] = pk_f16(v[0], v[1]);
    } else if (idx < 6000 + 23296) {
        // fc1 B-frag chunks: [(nt*13+ks)][lane][dw] ; n=lane&15, k=ks*32+(lane>>4)*8+dw*2
        int t = idx - 6000;
        int dw = t & 3, lane = (t >> 2) & 63, chunk = t >> 8;
        int ks = chunk % 13, nt = chunk / 13;
        int j = nt * 16 + (lane & 15);
        int k = ks * 32 + (lane >> 4) * 8 + dw * 2;
        float a = (j < HID && k     < 400) ? fc1_w[j * 400 + k]     : 0.f;
        float b = (j < HID && k + 1 < 400) ? fc1_w[j * 400 + k + 1] : 0.f;
        ws[WS_FC1 + t] = pk_f16(a, b);
    } else if (idx < 29296 + 3072) {
        int t = idx - 29296;
        int dw = t & 3, lane = (t >> 2) & 63, chunk = t >> 8;
        int ks = chunk % 4, nt = chunk / 4;
        int j = nt * 16 + (lane & 15);
        int k = ks * 32 + (lane >> 4) * 8 + dw * 2;
        float a = (j < TAGS && k     < HID) ? out_w[j * 100 + k]     : 0.f;
        float b = (j < TAGS && k + 1 < HID) ? out_w[j * 100 + k + 1] : 0.f;
        ws[WS_OUT + t] = pk_f16(a, b);
    }
}

// ---------------- feat: emb gather + conv/maxpool -> fp16 F rows in global ----------------
__global__ __launch_bounds__(256)
void feat(const int*   __restrict__ input,   // (B, 105)
          const float* __restrict__ emb,     // (WV, 50)
          const float* __restrict__ conv_b,  // (30)
          unsigned int* __restrict__ ws)
{
    __shared__ unsigned int Ths[6000];        // fp16 T tables, 24000 B

    const int tid   = threadIdx.x;
    const int item0 = blockIdx.x * 16;
    unsigned int* Fg = ws + WS_F;

    for (int idx = tid; idx < 6000; idx += 256) Ths[idx] = ws[WS_TH + idx];
    __syncthreads();

    // ---- zero K-pad dwords 200..207 per item ----
    if (tid < 128) Fg[(item0 + (tid >> 3)) * 208 + 200 + (tid & 7)] = 0;

    // ---- word embeddings ----
    for (int idx = tid; idx < 2000; idx += 256) {
        int ph = idx % 25;
        int w  = (idx / 25) % 5;
        int i  = idx / 125;
        int wid = input[(item0 + i) * 105 + w * 21];
        float2 e = *(const float2*)&emb[wid * 50 + ph * 2];
        Fg[(item0 + i) * 208 + w * 40 + ph] = pk_f16(e.x, e.y);
    }

    // ---- conv + maxpool: 4 lanes per (i,w), lane = 8 oc ----
    {
        const int q4  = tid & 3;
        const int oc0 = q4 * 8;
        h2v bias[4];
        #pragma unroll
        for (int d = 0; d < 4; ++d) {
            int a = oc0 + 2 * d, b = a + 1;
            bias[d].x = (_Float16)(a < OC ? conv_b[a] : 0.f);
            bias[d].y = (_Float16)(b < OC ? conv_b[b] : 0.f);
        }
        for (int task = tid >> 2; task < 80; task += 64) {
            int i = task / 5, w = task % 5;
            const int* cp = &input[(item0 + i) * 105 + w * 21 + 1];
            int c[20];
            #pragma unroll
            for (int p = 0; p < 20; ++p) c[p] = cp[p];
            h2v m[4];
            #pragma unroll
            for (int d = 0; d < 4; ++d) { m[d].x = (_Float16)(-30000.f); m[d].y = (_Float16)(-30000.f); }
            #pragma unroll 6
            for (int p = 0; p < 18; ++p) {
                uint4 ra = *(const uint4*)&Ths[c[p    ] * 20        + q4 * 4];
                uint4 rb = *(const uint4*)&Ths[c[p + 1] * 20 + 2000 + q4 * 4];
                uint4 rc = *(const uint4*)&Ths[c[p + 2] * 20 + 4000 + q4 * 4];
                unsigned int* pa = (unsigned int*)&ra;
                unsigned int* pb = (unsigned int*)&rb;
                unsigned int* pc = (unsigned int*)&rc;
                #pragma unroll
                for (int d = 0; d < 4; ++d) {
                    h2v s = u2h(pa[d]) + u2h(pb[d]) + u2h(pc[d]);
                    m[d] = __builtin_elementwise_max(m[d], s);
                }
            }
            int base = (item0 + i) * 208 + w * 40 + 25 + q4 * 4;
            Fg[base]     = h2u(m[0] + bias[0]);
            Fg[base + 1] = h2u(m[1] + bias[1]);
            Fg[base + 2] = h2u(m[2] + bias[2]);
            if (q4 < 3) Fg[base + 3] = h2u(m[3] + bias[3]);
        }
    }
}

// ---------------- gemm: fc1 (MFMA, A from global) + tanh + out layer ----------------
__global__ __launch_bounds__(256)
void gemm(const float* __restrict__ fc1_b,   // (100)
          const float* __restrict__ out_b,   // (36)
          const unsigned int* __restrict__ ws,
          float*       __restrict__ out)     // (B, 36)
{
    __shared__ unsigned int Hh[4][16 * 68];   // per-wave h slice, 4352 B each

    const int tid  = threadIdx.x;
    const int wv   = tid >> 6;
    const int lane = tid & 63;
    const int ln15 = lane & 15;
    const int quad = lane >> 4;
    const int item0 = blockIdx.x * 64 + wv * 16;
    unsigned int* Hw = &Hh[wv][0];
    const unsigned int* Fg = ws + WS_F;

    // ---- fc1: 13 K-steps, A streamed from global, 7 n-tiles ----
    f32x4 acc[7];
    #pragma unroll
    for (int t = 0; t < 7; ++t) acc[t] = f32x4{0, 0, 0, 0};
    {
        const uint4* wp = (const uint4*)(ws + WS_FC1);
        const unsigned int* arow = Fg + (item0 + ln15) * 208 + quad * 4;
        for (int ks = 0; ks < 13; ++ks) {
            half8 a = ash8(*(const uint4*)(arow + ks * 16));
            #pragma unroll
            for (int t = 0; t < 7; ++t) {
                uint4 bv = wp[(t * 13 + ks) * 64 + lane];
                acc[t] = __builtin_amdgcn_mfma_f32_16x16x32_f16(a, ash8(bv), acc[t], 0, 0, 0);
            }
        }
    }

    // ---- epilogue: tanh -> Hh (C-layout -> A-layout via LDS), zero K-pad ----
    {
        for (int t2 = lane; t2 < 224; t2 += 64) {
            int i = t2 / 14, d = t2 % 14;
            Hw[i * 68 + 50 + d] = 0;
        }
        unsigned short* Hs = (unsigned short*)Hw;
        #pragma unroll
        for (int t = 0; t < 7; ++t) {
            int j = t * 16 + ln15;
            if (j < HID) {
                float bj = fc1_b[j];
                #pragma unroll
                for (int r = 0; r < 4; ++r) {
                    int it = quad * 4 + r;
                    float hv = tanhf(acc[t][r] + bj);
                    _Float16 h = (_Float16)hv;
                    Hs[it * 136 + j] = *reinterpret_cast<unsigned short*>(&h);
                }
            }
        }
    }
    // same-wave LDS writes are visible to same-wave reads in-order: no barrier

    // ---- out layer: 3 n-tiles, K=128 ----
    {
        f32x4 oacc[3];
        #pragma unroll
        for (int t = 0; t < 3; ++t) oacc[t] = f32x4{0, 0, 0, 0};
        const uint4* wpo = (const uint4*)(ws + WS_OUT);
        const int aoff = ln15 * 68 + quad * 4;
        #pragma unroll
        for (int ks = 0; ks < 4; ++ks) {
            half8 a = ash8(*(const uint4*)&Hw[aoff + ks * 16]);
            #pragma unroll
            for (int t = 0; t < 3; ++t) {
                uint4 bv = wpo[(t * 4 + ks) * 64 + lane];
                oacc[t] = __builtin_amdgcn_mfma_f32_16x16x32_f16(a, ash8(bv), oacc[t], 0, 0, 0);
            }
        }
        #pragma unroll
        for (int t = 0; t < 3; ++t) {
            int o = t * 16 + ln15;
            if (o < TAGS) {
                float bo = out_b[o];
                #pragma unroll
                for (int r = 0; r < 4; ++r) {
                    int it = item0 + quad * 4 + r;
                    out[it * TAGS + o] = oacc[t][r] + bo;
                }
            }
        }
    }
}

extern "C" void kernel_launch(void* const* d_in, const int* in_sizes, int n_in,
                              void* d_out, int out_size, void* d_ws, size_t ws_size,
                              hipStream_t stream) {
    const int*   input  = (const int*)  d_in[0];
    const float* emb    = (const float*)d_in[1];
    const float* char_e = (const float*)d_in[2];
    const float* conv_w = (const float*)d_in[3];
    const float* conv_b = (const float*)d_in[4];
    const float* fc1_w  = (const float*)d_in[5];
    const float* fc1_b  = (const float*)d_in[6];
    const float* out_w  = (const float*)d_in[7];
    const float* out_b  = (const float*)d_in[8];
    unsigned int* ws = (unsigned int*)d_ws;

    prep<<<127, 256, 0, stream>>>(conv_w, char_e, fc1_w, out_w, ws);
    feat<<<B_TOT / 16, 256, 0, stream>>>(input, emb, conv_b, ws);
    gemm<<<B_TOT / 64, 256, 0, stream>>>(fc1_b, out_b, ws, (float*)d_out);
}